// Round 1
// baseline (253.300 us; speedup 1.0000x reference)
//
#include <hip/hip_runtime.h>
#include <hip/hip_bf16.h>

// Sizes (fixed by the problem)
#define BATCH 16
#define NQ    1024          // Nd == Ns == 1024
#define DM    256
#define NROWS (BATCH * NQ)  // 16384 rows per side
#define RINV  10.0f         // 1/REG

typedef float  f32x4 __attribute__((ext_vector_type(4)));
typedef short  s16x8 __attribute__((ext_vector_type(8)));

static __device__ __forceinline__ ushort f2bf(float f) {
    // round-to-nearest-even f32 -> bf16 (inputs are finite)
    unsigned u = __builtin_bit_cast(unsigned, f);
    u += 0x7fffu + ((u >> 16) & 1u);
    return (ushort)(u >> 16);
}

// ---------------------------------------------------------------- prep:
// convert Wq/Wk to bf16, zero the v potential
__global__ void k_prep(const float* __restrict__ Wq, const float* __restrict__ Wk,
                       ushort* __restrict__ wqb, ushort* __restrict__ wkb,
                       float* __restrict__ v) {
    int i = blockIdx.x * 256 + threadIdx.x;   // grid 256 -> i < 65536
    if (i < DM * DM) { wqb[i] = f2bf(Wq[i]); wkb[i] = f2bf(Wk[i]); }
    if (i < NROWS)    v[i] = 0.0f;
}

// ---------------------------------------------------------------- projection:
// per wave: 16 rows x 256 cols of (x @ W^T + b), L2-normalized, stored bf16.
// No LDS: A-frags loaded f32 from global + converted; B-frags (W bf16) are
// L2-resident (128 KB) and loaded as dwordx4 per lane.
__global__ void __launch_bounds__(256) k_proj(
        const float* __restrict__ drone, const float* __restrict__ sat,
        const ushort* __restrict__ wqb, const ushort* __restrict__ wkb,
        const float* __restrict__ bq, const float* __restrict__ bk,
        ushort* __restrict__ qk) {
    int t = threadIdx.x;
    int lane = t & 63, w = t >> 6;
    int row0 = blockIdx.x * 64 + w * 16;      // 0..32767, 16 rows per wave
    const float* x; const ushort* W; const float* bias;
    int rsrc = row0;
    if (row0 < NROWS) { x = drone; W = wqb; bias = bq; }
    else              { x = sat;   W = wkb; bias = bk; rsrc = row0 - NROWS; }

    int l16 = lane & 15, lh = lane >> 4;
    f32x4 acc[16];
#pragma unroll
    for (int n = 0; n < 16; n++) acc[n] = f32x4{0.f, 0.f, 0.f, 0.f};

    const float* arow = x + (size_t)(rsrc + l16) * DM;
#pragma unroll
    for (int kk = 0; kk < 8; kk++) {
        int k0 = kk * 32 + lh * 8;
        f32x4 a0 = *(const f32x4*)(arow + k0);
        f32x4 a1 = *(const f32x4*)(arow + k0 + 4);
        s16x8 av;
#pragma unroll
        for (int j = 0; j < 4; j++) {
            av[j]     = (short)f2bf(a0[j]);
            av[j + 4] = (short)f2bf(a1[j]);
        }
#pragma unroll
        for (int n = 0; n < 16; n++) {
            s16x8 bv = *(const s16x8*)(W + (size_t)(n * 16 + l16) * DM + k0);
            acc[n] = __builtin_amdgcn_mfma_f32_16x16x32_bf16(av, bv, acc[n], 0, 0, 0);
        }
    }
    // bias + row sum-of-squares (rows of this wave: lh*4 + r)
    float ssq[4] = {0.f, 0.f, 0.f, 0.f};
#pragma unroll
    for (int n = 0; n < 16; n++) {
        float bcol = bias[n * 16 + l16];
#pragma unroll
        for (int r = 0; r < 4; r++) {
            acc[n][r] += bcol;
            ssq[r] += acc[n][r] * acc[n][r];
        }
    }
#pragma unroll
    for (int off = 1; off < 16; off <<= 1) {
#pragma unroll
        for (int r = 0; r < 4; r++) ssq[r] += __shfl_xor(ssq[r], off);
    }
    float inv[4];
#pragma unroll
    for (int r = 0; r < 4; r++) inv[r] = 1.0f / fmaxf(sqrtf(ssq[r]), 1e-12f);
#pragma unroll
    for (int n = 0; n < 16; n++) {
#pragma unroll
        for (int r = 0; r < 4; r++) {
            qk[(size_t)(row0 + lh * 4 + r) * DM + n * 16 + l16] =
                f2bf(acc[n][r] * inv[r]);
        }
    }
}

// ---------------------------------------------------------------- cost GEMM:
// cost[b,n,m] = 1 - q[b,n,:] . k[b,m,:]  (bf16 MFMA, f32 out into d_out)
__global__ void __launch_bounds__(256) k_cost(const ushort* __restrict__ qk,
                                              float* __restrict__ cost) {
    int t = threadIdx.x, lane = t & 63, w = t >> 6;
    int l16 = lane & 15, lh = lane >> 4;
    int b = blockIdx.z;
    int rowbase = blockIdx.y * 128 + (w >> 1) * 64;
    int colbase = blockIdx.x * 128 + (w & 1) * 64;
    const ushort* Q = qk + (size_t)b * NQ * DM;
    const ushort* K = qk + (size_t)(NROWS + b * NQ) * DM;

    f32x4 acc[4][4];
#pragma unroll
    for (int i = 0; i < 4; i++)
#pragma unroll
        for (int j = 0; j < 4; j++) acc[i][j] = f32x4{0.f, 0.f, 0.f, 0.f};

#pragma unroll
    for (int kk = 0; kk < 8; kk++) {
        int k0 = kk * 32 + lh * 8;
        s16x8 am[4], bn[4];
#pragma unroll
        for (int mi = 0; mi < 4; mi++)
            am[mi] = *(const s16x8*)(Q + (size_t)(rowbase + mi * 16 + l16) * DM + k0);
#pragma unroll
        for (int ni = 0; ni < 4; ni++)
            bn[ni] = *(const s16x8*)(K + (size_t)(colbase + ni * 16 + l16) * DM + k0);
#pragma unroll
        for (int mi = 0; mi < 4; mi++)
#pragma unroll
            for (int ni = 0; ni < 4; ni++)
                acc[mi][ni] = __builtin_amdgcn_mfma_f32_16x16x32_bf16(
                    am[mi], bn[ni], acc[mi][ni], 0, 0, 0);
    }
    float* outb = cost + (size_t)b * NQ * NQ;
#pragma unroll
    for (int mi = 0; mi < 4; mi++) {
#pragma unroll
        for (int r = 0; r < 4; r++) {
            int row = rowbase + mi * 16 + lh * 4 + r;
#pragma unroll
            for (int ni = 0; ni < 4; ni++) {
                int col = colbase + ni * 16 + l16;
                outb[(size_t)row * NQ + col] = 1.0f - acc[mi][ni][r];
            }
        }
    }
}

// ---------------------------------------------------------------- row lse:
// u[b,n] = lse_m( -10*cost[b,n,m] - v[b,m] )
__global__ void __launch_bounds__(256) k_row_lse(const float* __restrict__ cost,
                                                 const float* __restrict__ v,
                                                 float* __restrict__ u) {
    int bn = blockIdx.x, b = bn >> 10, t = threadIdx.x;
    int lane = t & 63, w = t >> 6;
    f32x4 c  = *(const f32x4*)(cost + (size_t)bn * NQ + t * 4);
    f32x4 vv = *(const f32x4*)(v + (b << 10) + t * 4);
    float x[4];
#pragma unroll
    for (int j = 0; j < 4; j++) x[j] = fmaf(-RINV, c[j], -vv[j]);
    float m = fmaxf(fmaxf(x[0], x[1]), fmaxf(x[2], x[3]));
#pragma unroll
    for (int off = 32; off; off >>= 1) m = fmaxf(m, __shfl_xor(m, off));
    __shared__ float sm[4], ssh[4];
    if (lane == 0) sm[w] = m;
    __syncthreads();
    m = fmaxf(fmaxf(sm[0], sm[1]), fmaxf(sm[2], sm[3]));
    float s = 0.f;
#pragma unroll
    for (int j = 0; j < 4; j++) s += __expf(x[j] - m);
#pragma unroll
    for (int off = 32; off; off >>= 1) s += __shfl_xor(s, off);
    if (lane == 0) ssh[w] = s;
    __syncthreads();
    if (t == 0) u[bn] = m + __logf(ssh[0] + ssh[1] + ssh[2] + ssh[3]);
}

// ---------------------------------------------------------------- col lse, stage 1:
// online lse over an n-chunk of 256 rows; 64 columns per block.
__global__ void __launch_bounds__(256) k_colpart(const float* __restrict__ cost,
                                                 const float* __restrict__ u,
                                                 float2* __restrict__ part) {
    int t = threadIdx.x;
    int mloc = t & 63, w = t >> 6;
    int b = blockIdx.z;
    int m = blockIdx.x * 64 + mloc;
    int nbase = blockIdx.y * 256;
    const float* cb = cost + (size_t)b * NQ * NQ + m;
    const float* ub = u + (b << 10);
    float mx = -3.0e38f, s = 0.0f;
#pragma unroll 4
    for (int i = 0; i < 64; i++) {
        int n = nbase + w + i * 4;
        float xv = fmaf(-RINV, cb[(size_t)n * NQ], -ub[n]);
        float nm = fmaxf(mx, xv);
        s = s * __expf(mx - nm) + __expf(xv - nm);
        mx = nm;
    }
    __shared__ float sm[4][64], ss[4][64];
    sm[w][mloc] = mx; ss[w][mloc] = s;
    __syncthreads();
    if (w == 0) {
        float M = fmaxf(fmaxf(sm[0][mloc], sm[1][mloc]),
                        fmaxf(sm[2][mloc], sm[3][mloc]));
        float S = ss[0][mloc] * __expf(sm[0][mloc] - M)
                + ss[1][mloc] * __expf(sm[1][mloc] - M)
                + ss[2][mloc] * __expf(sm[2][mloc] - M)
                + ss[3][mloc] * __expf(sm[3][mloc] - M);
        part[((size_t)b * NQ + m) * 4 + blockIdx.y] = float2{M, S};
    }
}

// ---------------------------------------------------------------- col lse, stage 2:
__global__ void k_colcomb(const float2* __restrict__ part, float* __restrict__ v) {
    int idx = blockIdx.x * 256 + threadIdx.x;   // 0..16383 == b*1024 + m
    float2 p0 = part[idx * 4 + 0], p1 = part[idx * 4 + 1];
    float2 p2 = part[idx * 4 + 2], p3 = part[idx * 4 + 3];
    float M = fmaxf(fmaxf(p0.x, p1.x), fmaxf(p2.x, p3.x));
    float S = p0.y * __expf(p0.x - M) + p1.y * __expf(p1.x - M)
            + p2.y * __expf(p2.x - M) + p3.y * __expf(p3.x - M);
    v[idx] = M + __logf(S);
}

// ---------------------------------------------------------------- final:
// plan = exp(-10*cost - u - v) (overwrites cost in d_out), partial ot sums.
__global__ void __launch_bounds__(256) k_final(float* __restrict__ costplan,
                                               const float* __restrict__ u,
                                               const float* __restrict__ v,
                                               float* __restrict__ part) {
    int bn = blockIdx.x, b = bn >> 10, t = threadIdx.x;
    int lane = t & 63, w = t >> 6;
    size_t off = (size_t)bn * NQ + t * 4;
    f32x4 c  = *(const f32x4*)(costplan + off);
    f32x4 vv = *(const f32x4*)(v + (b << 10) + t * 4);
    float uu = u[bn];
    f32x4 p; float s = 0.f;
#pragma unroll
    for (int j = 0; j < 4; j++) {
        p[j] = __expf(fmaf(-RINV, c[j], -uu - vv[j]));
        s = fmaf(p[j], c[j], s);
    }
    *(f32x4*)(costplan + off) = p;
#pragma unroll
    for (int o = 32; o; o >>= 1) s += __shfl_xor(s, o);
    __shared__ float sm[4];
    if (lane == 0) sm[w] = s;
    __syncthreads();
    if (t == 0) part[bn] = sm[0] + sm[1] + sm[2] + sm[3];
}

__global__ void k_reduce(const float* __restrict__ part, float* __restrict__ out) {
    int t = threadIdx.x;
    float s = 0.f;
    for (int i = t; i < NROWS; i += 256) s += part[i];
#pragma unroll
    for (int o = 32; o; o >>= 1) s += __shfl_xor(s, o);
    __shared__ float sm[4];
    if ((t & 63) == 0) sm[t >> 6] = s;
    __syncthreads();
    if (t == 0) out[(size_t)BATCH * NQ * NQ] = (sm[0] + sm[1] + sm[2] + sm[3]) * (1.0f / BATCH);
}

// ---------------------------------------------------------------- launch
extern "C" void kernel_launch(void* const* d_in, const int* in_sizes, int n_in,
                              void* d_out, int out_size, void* d_ws, size_t ws_size,
                              hipStream_t stream) {
    const float* drone = (const float*)d_in[0];
    const float* sat   = (const float*)d_in[1];
    const float* Wq    = (const float*)d_in[2];
    const float* bq    = (const float*)d_in[3];
    const float* Wk    = (const float*)d_in[4];
    const float* bk    = (const float*)d_in[5];
    float* out = (float*)d_out;

    char* ws = (char*)d_ws;
    ushort* wqb   = (ushort*)(ws);                    // 128 KB
    ushort* wkb   = (ushort*)(ws + (131072));         // 128 KB
    ushort* qk    = (ushort*)(ws + (262144));         // 16 MB  (Q rows 0..16383, K rows 16384..32767)
    float*  u     = (float*)(ws + 17039360);          // 64 KB
    float*  v     = (float*)(ws + 17104896);          // 64 KB
    float2* cpart = (float2*)(ws + 17170432);         // 512 KB
    float*  bpart = (float*)(ws + 17694720);          // 64 KB

    float* cost = out;  // d_out doubles as the 67 MB cost scratch; k_final overwrites with plan

    k_prep<<<256, 256, 0, stream>>>(Wq, Wk, wqb, wkb, v);
    k_proj<<<512, 256, 0, stream>>>(drone, sat, wqb, wkb, bq, bk, qk);
    k_cost<<<dim3(8, 8, BATCH), 256, 0, stream>>>(qk, cost);
    for (int it = 0; it < 5; it++) {
        k_row_lse<<<NROWS, 256, 0, stream>>>(cost, v, u);
        k_colpart<<<dim3(16, 4, BATCH), 256, 0, stream>>>(cost, u, cpart);
        k_colcomb<<<64, 256, 0, stream>>>(cpart, v);
    }
    k_final<<<NROWS, 256, 0, stream>>>(cost, u, v, bpart);
    k_reduce<<<1, 256, 0, stream>>>(bpart, out);
}

// Round 2
// 251.717 us; speedup vs baseline: 1.0063x; 1.0063x over previous
//
#include <hip/hip_runtime.h>
#include <hip/hip_bf16.h>

// Sizes (fixed by the problem)
#define BATCH 16
#define NQ    1024          // Nd == Ns == 1024
#define DM    256
#define NROWS (BATCH * NQ)  // 16384 rows per side
#define RINV  10.0f         // 1/REG

typedef float  f32x4 __attribute__((ext_vector_type(4)));
typedef short  s16x8 __attribute__((ext_vector_type(8)));

static __device__ __forceinline__ ushort f2bf(float f) {
    // round-to-nearest-even f32 -> bf16 (inputs are finite)
    unsigned u = __builtin_bit_cast(unsigned, f);
    u += 0x7fffu + ((u >> 16) & 1u);
    return (ushort)(u >> 16);
}

// ---------------------------------------------------------------- prep:
// convert Wq/Wk to bf16, zero the v potential
__global__ void k_prep(const float* __restrict__ Wq, const float* __restrict__ Wk,
                       ushort* __restrict__ wqb, ushort* __restrict__ wkb,
                       float* __restrict__ v) {
    int i = blockIdx.x * 256 + threadIdx.x;   // grid 256 -> i < 65536
    if (i < DM * DM) { wqb[i] = f2bf(Wq[i]); wkb[i] = f2bf(Wk[i]); }
    if (i < NROWS)    v[i] = 0.0f;
}

// ---------------------------------------------------------------- projection:
// 2048 blocks x 256 thr. Block = 16 rows; wave w = 64-col slice.
// A-tile (16x256 f32) staged in LDS (padded stride 260 -> conflict-free);
// B (W bf16, 128 KB) L2-resident. Cross-wave ssq reduce in LDS.
__global__ void __launch_bounds__(256) k_proj(
        const float* __restrict__ drone, const float* __restrict__ sat,
        const ushort* __restrict__ wqb, const ushort* __restrict__ wkb,
        const float* __restrict__ bq, const float* __restrict__ bk,
        ushort* __restrict__ qk) {
    __shared__ float As[16][260];
    __shared__ float red[4][16];

    int t = threadIdx.x;
    int lane = t & 63, w = t >> 6;
    int l16 = lane & 15, lh = lane >> 4;
    int row0 = blockIdx.x * 16;               // 0..32767
    const float* x; const ushort* W; const float* bias;
    int rsrc = row0;
    if (row0 < NROWS) { x = drone; W = wqb; bias = bq; }
    else              { x = sat;   W = wkb; bias = bk; rsrc = row0 - NROWS; }

    // ---- stage A: 16 rows x 256 f32, coalesced 256B segments per 16-thread group
    {
        int r = t >> 4, c0 = (t & 15) * 4;
        const float* g = x + (size_t)(rsrc + r) * DM;
#pragma unroll
        for (int j = 0; j < 4; j++) {
            int c = c0 + j * 64;
            *(f32x4*)&As[r][c] = *(const f32x4*)(g + c);
        }
    }
    __syncthreads();

    // ---- MFMA: wave covers cols w*64 .. w*64+63 (4 frags)
    f32x4 acc[4];
#pragma unroll
    for (int ni = 0; ni < 4; ni++) acc[ni] = f32x4{0.f, 0.f, 0.f, 0.f};

    int colbase = w * 64;
#pragma unroll
    for (int kk = 0; kk < 8; kk++) {
        int k0 = kk * 32 + lh * 8;
        f32x4 a0 = *(const f32x4*)&As[l16][k0];
        f32x4 a1 = *(const f32x4*)&As[l16][k0 + 4];
        s16x8 av;
#pragma unroll
        for (int j = 0; j < 4; j++) {
            av[j]     = (short)f2bf(a0[j]);
            av[j + 4] = (short)f2bf(a1[j]);
        }
#pragma unroll
        for (int ni = 0; ni < 4; ni++) {
            s16x8 bv = *(const s16x8*)(W + (size_t)(colbase + ni * 16 + l16) * DM + k0);
            acc[ni] = __builtin_amdgcn_mfma_f32_16x16x32_bf16(av, bv, acc[ni], 0, 0, 0);
        }
    }

    // ---- bias + partial ssq over this wave's 64 cols
    float ssq[4] = {0.f, 0.f, 0.f, 0.f};
#pragma unroll
    for (int ni = 0; ni < 4; ni++) {
        float bcol = bias[colbase + ni * 16 + l16];
#pragma unroll
        for (int r = 0; r < 4; r++) {
            acc[ni][r] += bcol;
            ssq[r] += acc[ni][r] * acc[ni][r];
        }
    }
#pragma unroll
    for (int off = 1; off < 16; off <<= 1) {
#pragma unroll
        for (int r = 0; r < 4; r++) ssq[r] += __shfl_xor(ssq[r], off);
    }
    if (l16 == 0) {
#pragma unroll
        for (int r = 0; r < 4; r++) red[w][lh * 4 + r] = ssq[r];
    }
    __syncthreads();

    float inv[4];
#pragma unroll
    for (int r = 0; r < 4; r++) {
        int row = lh * 4 + r;
        float tot = red[0][row] + red[1][row] + red[2][row] + red[3][row];
        inv[r] = 1.0f / fmaxf(sqrtf(tot), 1e-12f);
    }
#pragma unroll
    for (int ni = 0; ni < 4; ni++) {
#pragma unroll
        for (int r = 0; r < 4; r++) {
            qk[(size_t)(row0 + lh * 4 + r) * DM + colbase + ni * 16 + l16] =
                f2bf(acc[ni][r] * inv[r]);
        }
    }
}

// ---------------------------------------------------------------- cost GEMM:
// cost[b,n,m] = 1 - q[b,n,:] . k[b,m,:]  (bf16 MFMA, f32 out into d_out)
__global__ void __launch_bounds__(256) k_cost(const ushort* __restrict__ qk,
                                              float* __restrict__ cost) {
    int t = threadIdx.x, lane = t & 63, w = t >> 6;
    int l16 = lane & 15, lh = lane >> 4;
    int b = blockIdx.z;
    int rowbase = blockIdx.y * 128 + (w >> 1) * 64;
    int colbase = blockIdx.x * 128 + (w & 1) * 64;
    const ushort* Q = qk + (size_t)b * NQ * DM;
    const ushort* K = qk + (size_t)(NROWS + b * NQ) * DM;

    f32x4 acc[4][4];
#pragma unroll
    for (int i = 0; i < 4; i++)
#pragma unroll
        for (int j = 0; j < 4; j++) acc[i][j] = f32x4{0.f, 0.f, 0.f, 0.f};

#pragma unroll
    for (int kk = 0; kk < 8; kk++) {
        int k0 = kk * 32 + lh * 8;
        s16x8 am[4], bn[4];
#pragma unroll
        for (int mi = 0; mi < 4; mi++)
            am[mi] = *(const s16x8*)(Q + (size_t)(rowbase + mi * 16 + l16) * DM + k0);
#pragma unroll
        for (int ni = 0; ni < 4; ni++)
            bn[ni] = *(const s16x8*)(K + (size_t)(colbase + ni * 16 + l16) * DM + k0);
#pragma unroll
        for (int mi = 0; mi < 4; mi++)
#pragma unroll
            for (int ni = 0; ni < 4; ni++)
                acc[mi][ni] = __builtin_amdgcn_mfma_f32_16x16x32_bf16(
                    am[mi], bn[ni], acc[mi][ni], 0, 0, 0);
    }
    float* outb = cost + (size_t)b * NQ * NQ;
#pragma unroll
    for (int mi = 0; mi < 4; mi++) {
#pragma unroll
        for (int r = 0; r < 4; r++) {
            int row = rowbase + mi * 16 + lh * 4 + r;
#pragma unroll
            for (int ni = 0; ni < 4; ni++) {
                int col = colbase + ni * 16 + l16;
                outb[(size_t)row * NQ + col] = 1.0f - acc[mi][ni][r];
            }
        }
    }
}

// ---------------------------------------------------------------- row lse:
// u[b,n] = lse_m( -10*cost[b,n,m] - v[b,m] )
__global__ void __launch_bounds__(256) k_row_lse(const float* __restrict__ cost,
                                                 const float* __restrict__ v,
                                                 float* __restrict__ u) {
    int bn = blockIdx.x, b = bn >> 10, t = threadIdx.x;
    int lane = t & 63, w = t >> 6;
    f32x4 c  = *(const f32x4*)(cost + (size_t)bn * NQ + t * 4);
    f32x4 vv = *(const f32x4*)(v + (b << 10) + t * 4);
    float x[4];
#pragma unroll
    for (int j = 0; j < 4; j++) x[j] = fmaf(-RINV, c[j], -vv[j]);
    float m = fmaxf(fmaxf(x[0], x[1]), fmaxf(x[2], x[3]));
#pragma unroll
    for (int off = 32; off; off >>= 1) m = fmaxf(m, __shfl_xor(m, off));
    __shared__ float sm[4], ssh[4];
    if (lane == 0) sm[w] = m;
    __syncthreads();
    m = fmaxf(fmaxf(sm[0], sm[1]), fmaxf(sm[2], sm[3]));
    float s = 0.f;
#pragma unroll
    for (int j = 0; j < 4; j++) s += __expf(x[j] - m);
#pragma unroll
    for (int off = 32; off; off >>= 1) s += __shfl_xor(s, off);
    if (lane == 0) ssh[w] = s;
    __syncthreads();
    if (t == 0) u[bn] = m + __logf(ssh[0] + ssh[1] + ssh[2] + ssh[3]);
}

// ---------------------------------------------------------------- col lse, stage 1:
// online lse over an n-chunk of 256 rows; 64 columns per block.
__global__ void __launch_bounds__(256) k_colpart(const float* __restrict__ cost,
                                                 const float* __restrict__ u,
                                                 float2* __restrict__ part) {
    int t = threadIdx.x;
    int mloc = t & 63, w = t >> 6;
    int b = blockIdx.z;
    int m = blockIdx.x * 64 + mloc;
    int nbase = blockIdx.y * 256;
    const float* cb = cost + (size_t)b * NQ * NQ + m;
    const float* ub = u + (b << 10);
    float mx = -3.0e38f, s = 0.0f;
#pragma unroll 4
    for (int i = 0; i < 64; i++) {
        int n = nbase + w + i * 4;
        float xv = fmaf(-RINV, cb[(size_t)n * NQ], -ub[n]);
        float nm = fmaxf(mx, xv);
        s = s * __expf(mx - nm) + __expf(xv - nm);
        mx = nm;
    }
    __shared__ float sm[4][64], ss[4][64];
    sm[w][mloc] = mx; ss[w][mloc] = s;
    __syncthreads();
    if (w == 0) {
        float M = fmaxf(fmaxf(sm[0][mloc], sm[1][mloc]),
                        fmaxf(sm[2][mloc], sm[3][mloc]));
        float S = ss[0][mloc] * __expf(sm[0][mloc] - M)
                + ss[1][mloc] * __expf(sm[1][mloc] - M)
                + ss[2][mloc] * __expf(sm[2][mloc] - M)
                + ss[3][mloc] * __expf(sm[3][mloc] - M);
        part[((size_t)b * NQ + m) * 4 + blockIdx.y] = float2{M, S};
    }
}

// ---------------------------------------------------------------- col lse, stage 2:
__global__ void k_colcomb(const float2* __restrict__ part, float* __restrict__ v) {
    int idx = blockIdx.x * 256 + threadIdx.x;   // 0..16383 == b*1024 + m
    float2 p0 = part[idx * 4 + 0], p1 = part[idx * 4 + 1];
    float2 p2 = part[idx * 4 + 2], p3 = part[idx * 4 + 3];
    float M = fmaxf(fmaxf(p0.x, p1.x), fmaxf(p2.x, p3.x));
    float S = p0.y * __expf(p0.x - M) + p1.y * __expf(p1.x - M)
            + p2.y * __expf(p2.x - M) + p3.y * __expf(p3.x - M);
    v[idx] = M + __logf(S);
}

// ---------------------------------------------------------------- final:
// plan = exp(-10*cost - u - v) (overwrites cost in d_out), partial ot sums.
__global__ void __launch_bounds__(256) k_final(float* __restrict__ costplan,
                                               const float* __restrict__ u,
                                               const float* __restrict__ v,
                                               float* __restrict__ part) {
    int bn = blockIdx.x, b = bn >> 10, t = threadIdx.x;
    int lane = t & 63, w = t >> 6;
    size_t off = (size_t)bn * NQ + t * 4;
    f32x4 c  = *(const f32x4*)(costplan + off);
    f32x4 vv = *(const f32x4*)(v + (b << 10) + t * 4);
    float uu = u[bn];
    f32x4 p; float s = 0.f;
#pragma unroll
    for (int j = 0; j < 4; j++) {
        p[j] = __expf(fmaf(-RINV, c[j], -uu - vv[j]));
        s = fmaf(p[j], c[j], s);
    }
    *(f32x4*)(costplan + off) = p;
#pragma unroll
    for (int o = 32; o; o >>= 1) s += __shfl_xor(s, o);
    __shared__ float sm[4];
    if (lane == 0) sm[w] = s;
    __syncthreads();
    if (t == 0) part[bn] = sm[0] + sm[1] + sm[2] + sm[3];
}

__global__ void k_reduce(const float* __restrict__ part, float* __restrict__ out) {
    int t = threadIdx.x;
    float s = 0.f;
    for (int i = t; i < NROWS; i += 256) s += part[i];
#pragma unroll
    for (int o = 32; o; o >>= 1) s += __shfl_xor(s, o);
    __shared__ float sm[4];
    if ((t & 63) == 0) sm[t >> 6] = s;
    __syncthreads();
    if (t == 0) out[(size_t)BATCH * NQ * NQ] = (sm[0] + sm[1] + sm[2] + sm[3]) * (1.0f / BATCH);
}

// ---------------------------------------------------------------- launch
extern "C" void kernel_launch(void* const* d_in, const int* in_sizes, int n_in,
                              void* d_out, int out_size, void* d_ws, size_t ws_size,
                              hipStream_t stream) {
    const float* drone = (const float*)d_in[0];
    const float* sat   = (const float*)d_in[1];
    const float* Wq    = (const float*)d_in[2];
    const float* bq    = (const float*)d_in[3];
    const float* Wk    = (const float*)d_in[4];
    const float* bk    = (const float*)d_in[5];
    float* out = (float*)d_out;

    char* ws = (char*)d_ws;
    ushort* wqb   = (ushort*)(ws);                    // 128 KB
    ushort* wkb   = (ushort*)(ws + (131072));         // 128 KB
    ushort* qk    = (ushort*)(ws + (262144));         // 16 MB  (Q rows 0..16383, K rows 16384..32767)
    float*  u     = (float*)(ws + 17039360);          // 64 KB
    float*  v     = (float*)(ws + 17104896);          // 64 KB
    float2* cpart = (float2*)(ws + 17170432);         // 512 KB
    float*  bpart = (float*)(ws + 17694720);          // 64 KB

    float* cost = out;  // d_out doubles as the 67 MB cost scratch; k_final overwrites with plan

    k_prep<<<256, 256, 0, stream>>>(Wq, Wk, wqb, wkb, v);
    k_proj<<<2048, 256, 0, stream>>>(drone, sat, wqb, wkb, bq, bk, qk);
    k_cost<<<dim3(8, 8, BATCH), 256, 0, stream>>>(qk, cost);
    for (int it = 0; it < 5; it++) {
        k_row_lse<<<NROWS, 256, 0, stream>>>(cost, v, u);
        k_colpart<<<dim3(16, 4, BATCH), 256, 0, stream>>>(cost, u, cpart);
        k_colcomb<<<64, 256, 0, stream>>>(cpart, v);
    }
    k_final<<<NROWS, 256, 0, stream>>>(cost, u, v, bpart);
    k_reduce<<<1, 256, 0, stream>>>(bpart, out);
}

// Round 5
// 187.673 us; speedup vs baseline: 1.3497x; 1.3413x over previous
//
#include <hip/hip_runtime.h>
#include <hip/hip_bf16.h>

// Sizes (fixed by the problem)
#define BATCH 16
#define NQ    1024
#define DM    256
#define NROWS (BATCH * NQ)   // 16384 rows per side
#define RINV  10.0f          // 1/REG

typedef float  f32x4 __attribute__((ext_vector_type(4)));
typedef short  s16x8 __attribute__((ext_vector_type(8)));

static __device__ __forceinline__ ushort f2bf(float f) {
    // round-to-nearest-even f32 -> bf16 (inputs are finite)
    unsigned u = __builtin_bit_cast(unsigned, f);
    u += 0x7fffu + ((u >> 16) & 1u);
    return (ushort)(u >> 16);
}

// Fragment-packed layout: for 16-row group g, k-chunk kk (K=32), lane=lh*16+l16
// holds 8 bf16 of row (g*16+l16), k = kk*32+lh*8..+7, at buf[((g*8+kk)*64+lane)*8].
// Fragment loads become 1KB fully-coalesced wave reads (fixes the 64-cache-line
// scatter that pinned k_proj at 42us in rounds 1-2).

// ---------------------------------------------------------------- P0: pack W
__global__ void __launch_bounds__(256) k_prep(const float* __restrict__ Wq,
                                              const float* __restrict__ Wk,
                                              ushort* __restrict__ wp0,
                                              ushort* __restrict__ wp1) {
    int gid = blockIdx.x * 256 + threadIdx.x;   // 64 blocks -> gid < 16384
    const float* Wsrc = (gid < 8192) ? Wq : Wk;
    ushort* dst = (gid < 8192) ? wp0 : wp1;
    int gx = gid & 8191;
    int gcol = gx >> 9, kk = (gx >> 6) & 7, ln = gx & 63;
    const float* srow = Wsrc + (size_t)(gcol * 16 + (ln & 15)) * DM
                             + kk * 32 + (ln >> 4) * 8;
    ushort* d = dst + (size_t)gx * 8;
#pragma unroll
    for (int e = 0; e < 8; e++) d[e] = f2bf(srow[e]);
}

// ---------------------------------------------------------------- P1: projection
// 2048 blocks; block = 16 rows x 256 cols; wave = 64-col slice. A staged in LDS,
// B fragment-packed (1KB coalesced loads). Epilogue: bias, L2-normalize, LDS
// transpose into fragment-packed qkp.
__global__ void __launch_bounds__(256) k_proj(
        const float* __restrict__ drone, const float* __restrict__ sat,
        const ushort* __restrict__ wp0, const ushort* __restrict__ wp1,
        const float* __restrict__ bq, const float* __restrict__ bk,
        ushort* __restrict__ qkp) {
    __shared__ union {
        float  As[16][260];
        ushort S[16][280];
    } AB;
    __shared__ float red[4][16];

    int t = threadIdx.x;
    int lane = t & 63, w = t >> 6, l16 = lane & 15, lh = lane >> 4;
    int g = blockIdx.x;            // 16-row group 0..2047
    int row0 = g * 16;
    const float* x; const ushort* Wp; const float* bias; int rsrc;
    if (row0 < NROWS) { x = drone; Wp = wp0; bias = bq; rsrc = row0; }
    else              { x = sat;   Wp = wp1; bias = bk; rsrc = row0 - NROWS; }

    {   // stage 16x256 f32 A-tile, coalesced
        int r = t >> 4, c0 = (t & 15) * 4;
        const float* gp = x + (size_t)(rsrc + r) * DM;
#pragma unroll
        for (int j = 0; j < 4; j++)
            *(f32x4*)&AB.As[r][c0 + j * 64] = *(const f32x4*)(gp + c0 + j * 64);
    }
    __syncthreads();

    f32x4 acc[4];
#pragma unroll
    for (int ni = 0; ni < 4; ni++) acc[ni] = f32x4{0.f, 0.f, 0.f, 0.f};
#pragma unroll
    for (int kk = 0; kk < 8; kk++) {
        int k0 = kk * 32 + lh * 8;
        f32x4 a0 = *(const f32x4*)&AB.As[l16][k0];
        f32x4 a1 = *(const f32x4*)&AB.As[l16][k0 + 4];
        s16x8 av;
#pragma unroll
        for (int j = 0; j < 4; j++) {
            av[j]     = (short)f2bf(a0[j]);
            av[j + 4] = (short)f2bf(a1[j]);
        }
#pragma unroll
        for (int ni = 0; ni < 4; ni++) {
            s16x8 bv = *(const s16x8*)(Wp + ((size_t)((w * 4 + ni) * 8 + kk) * 64 + lane) * 8);
            acc[ni] = __builtin_amdgcn_mfma_f32_16x16x32_bf16(av, bv, acc[ni], 0, 0, 0);
        }
    }
    // bias + cross-wave row ssq
    float ssq[4] = {0.f, 0.f, 0.f, 0.f};
#pragma unroll
    for (int ni = 0; ni < 4; ni++) {
        float bcol = bias[w * 64 + ni * 16 + l16];
#pragma unroll
        for (int r = 0; r < 4; r++) {
            acc[ni][r] += bcol;
            ssq[r] += acc[ni][r] * acc[ni][r];
        }
    }
#pragma unroll
    for (int off = 1; off < 16; off <<= 1)
#pragma unroll
        for (int r = 0; r < 4; r++) ssq[r] += __shfl_xor(ssq[r], off);
    if (l16 == 0)
#pragma unroll
        for (int r = 0; r < 4; r++) red[w][lh * 4 + r] = ssq[r];
    __syncthreads();   // red visible; all As reads done before S overwrite

    float inv[4];
#pragma unroll
    for (int r = 0; r < 4; r++) {
        int row = lh * 4 + r;
        float tot = red[0][row] + red[1][row] + red[2][row] + red[3][row];
        inv[r] = 1.0f / fmaxf(sqrtf(tot), 1e-12f);
    }
    // transpose through LDS into fragment-packed order
#pragma unroll
    for (int ni = 0; ni < 4; ni++)
#pragma unroll
        for (int r = 0; r < 4; r++)
            AB.S[lh * 4 + r][w * 64 + ni * 16 + l16] = f2bf(acc[ni][r] * inv[r]);
    __syncthreads();
#pragma unroll
    for (int h = 0; h < 2; h++) {
        int kk = w + h * 4;
        s16x8 vv = *(const s16x8*)&AB.S[l16][kk * 32 + lh * 8];
        *(s16x8*)(qkp + ((size_t)(g * 8 + kk) * 64 + lane) * 8) = vv;
    }
}

// ---------------------------------------------------------------- P2: cost GEMM
// 1024 blocks; 128x128 tile; all operands fragment-packed (coalesced 1KB reads).
__global__ void __launch_bounds__(256) k_cost(const ushort* __restrict__ qkp,
                                              float* __restrict__ cost) {
    int t = threadIdx.x, lane = t & 63, w = t >> 6;
    int l16 = lane & 15, lh = lane >> 4;
    int tile = blockIdx.x;
    int b = tile >> 6, ty = (tile >> 3) & 7, tx = tile & 7;
    int rg  = b * 64 + ty * 8 + (w >> 1) * 4;          // Q group base
    int cgp = 1024 + b * 64 + tx * 8 + (w & 1) * 4;    // K group base
    f32x4 acc[4][4];
#pragma unroll
    for (int i = 0; i < 4; i++)
#pragma unroll
        for (int j = 0; j < 4; j++) acc[i][j] = f32x4{0.f, 0.f, 0.f, 0.f};
#pragma unroll
    for (int kk = 0; kk < 8; kk++) {
        s16x8 am[4], bn[4];
#pragma unroll
        for (int mi = 0; mi < 4; mi++)
            am[mi] = *(const s16x8*)(qkp + ((size_t)((rg + mi) * 8 + kk) * 64 + lane) * 8);
#pragma unroll
        for (int ni = 0; ni < 4; ni++)
            bn[ni] = *(const s16x8*)(qkp + ((size_t)((cgp + ni) * 8 + kk) * 64 + lane) * 8);
#pragma unroll
        for (int mi = 0; mi < 4; mi++)
#pragma unroll
            for (int ni = 0; ni < 4; ni++)
                acc[mi][ni] = __builtin_amdgcn_mfma_f32_16x16x32_bf16(
                    am[mi], bn[ni], acc[mi][ni], 0, 0, 0);
    }
    float* ob = cost + (size_t)b * NQ * NQ;
    int rl = ty * 128 + (w >> 1) * 64, cl = tx * 128 + (w & 1) * 64;
#pragma unroll
    for (int mi = 0; mi < 4; mi++)
#pragma unroll
        for (int r = 0; r < 4; r++) {
            int row = rl + mi * 16 + lh * 4 + r;
#pragma unroll
            for (int ni = 0; ni < 4; ni++)
                ob[(size_t)row * NQ + cl + ni * 16 + l16] = 1.0f - acc[mi][ni][r];
        }
}

// ---------------------------------------------------------------- row pass:
// u[row] = log sum_m exp(-10c - v[m]); v recombined from col partials in LDS.
// 512 blocks x 32 rows. No max-shift (args bounded, see analysis).
__global__ void __launch_bounds__(256) k_row(const float* __restrict__ cost,
                                             const float* __restrict__ part,
                                             float* __restrict__ u, int first) {
    __shared__ float vsh[NQ];
    int bid = blockIdx.x, t = threadIdx.x;
    int lane = t & 63, w = t >> 6;
    int b = bid >> 5;                       // 32 blocks per batch
    if (first) {
#pragma unroll
        for (int j = 0; j < 4; j++) vsh[t * 4 + j] = 0.f;
    } else {
        const f32x4* pp = (const f32x4*)&part[((size_t)(b << 10) + t * 4) * 2];
        f32x4 A = pp[0], B = pp[1];
        vsh[t * 4 + 0] = __logf(A[0] + A[1]);
        vsh[t * 4 + 1] = __logf(A[2] + A[3]);
        vsh[t * 4 + 2] = __logf(B[0] + B[1]);
        vsh[t * 4 + 3] = __logf(B[2] + B[3]);
    }
    __syncthreads();

#pragma unroll
    for (int rr = 0; rr < 8; rr++) {
        int row = bid * 32 + w * 8 + rr;
        const float* cr = cost + (size_t)row * NQ;
        float s0 = 0.f, s1 = 0.f, s2 = 0.f, s3 = 0.f;
#pragma unroll
        for (int j = 0; j < 4; j++) {
            f32x4 c4 = *(const f32x4*)(cr + j * 256 + lane * 4);
            f32x4 v4 = *(const f32x4*)&vsh[j * 256 + lane * 4];
            s0 += __expf(fmaf(-RINV, c4[0], -v4[0]));
            s1 += __expf(fmaf(-RINV, c4[1], -v4[1]));
            s2 += __expf(fmaf(-RINV, c4[2], -v4[2]));
            s3 += __expf(fmaf(-RINV, c4[3], -v4[3]));
        }
        float s = (s0 + s1) + (s2 + s3);
#pragma unroll
        for (int o = 32; o; o >>= 1) s += __shfl_xor(s, o);
        if (lane == 0) u[row] = __logf(s);
    }
}

// ---------------------------------------------------------------- col pass:
// part[b,m,nh] = sum over 512-row chunk of exp(-10c - u[n]); 64 cols per block.
__global__ void __launch_bounds__(256) k_col(const float* __restrict__ cost,
                                             const float* __restrict__ u,
                                             float* __restrict__ part) {
    __shared__ float ssm[4][64];
    int bid = blockIdx.x, t = threadIdx.x;
    int lane = t & 63, w = t >> 6;
    int b = bid >> 5, mg = (bid >> 1) & 15, nh = bid & 1;
    int m = mg * 64 + lane, n0 = nh * 512;
    const float* cb = cost + (size_t)b * NQ * NQ + m;
    const float* ub = u + (b << 10);
    float s0 = 0.f, s1 = 0.f, s2 = 0.f, s3 = 0.f;
#pragma unroll 2
    for (int i = 0; i < 128; i += 4) {
        int n = n0 + w + i * 4;
        s0 += __expf(fmaf(-RINV, cb[(size_t)(n     ) * NQ], -ub[n     ]));
        s1 += __expf(fmaf(-RINV, cb[(size_t)(n +  4) * NQ], -ub[n +  4]));
        s2 += __expf(fmaf(-RINV, cb[(size_t)(n +  8) * NQ], -ub[n +  8]));
        s3 += __expf(fmaf(-RINV, cb[(size_t)(n + 12) * NQ], -ub[n + 12]));
    }
    ssm[w][lane] = (s0 + s1) + (s2 + s3);
    __syncthreads();
    if (w == 0)
        part[((size_t)(b << 10) + m) * 2 + nh] =
            ssm[0][lane] + ssm[1][lane] + ssm[2][lane] + ssm[3][lane];
}

// ---------------------------------------------------------------- final:
// v from partials; plan = exp(-10c - u - v) overwrites cost; block dot-partials.
__global__ void __launch_bounds__(256) k_final(float* __restrict__ costplan,
                                               const float* __restrict__ part,
                                               const float* __restrict__ u,
                                               float* __restrict__ bprt) {
    __shared__ float vsh[NQ];
    __shared__ float red[4];
    int bid = blockIdx.x, t = threadIdx.x;
    int lane = t & 63, w = t >> 6;
    int b = bid >> 5;
    {
        const f32x4* pp = (const f32x4*)&part[((size_t)(b << 10) + t * 4) * 2];
        f32x4 A = pp[0], B = pp[1];
        vsh[t * 4 + 0] = __logf(A[0] + A[1]);
        vsh[t * 4 + 1] = __logf(A[2] + A[3]);
        vsh[t * 4 + 2] = __logf(B[0] + B[1]);
        vsh[t * 4 + 3] = __logf(B[2] + B[3]);
    }
    __syncthreads();

    float sacc = 0.f;
#pragma unroll
    for (int rr = 0; rr < 8; rr++) {
        int row = bid * 32 + w * 8 + rr;
        float* cr = costplan + (size_t)row * NQ;
        float uu = u[row];
#pragma unroll
        for (int j = 0; j < 4; j++) {
            f32x4 c4 = *(const f32x4*)(cr + j * 256 + lane * 4);
            f32x4 v4 = *(const f32x4*)&vsh[j * 256 + lane * 4];
            f32x4 p4;
#pragma unroll
            for (int e = 0; e < 4; e++) {
                p4[e] = __expf(fmaf(-RINV, c4[e], -uu - v4[e]));
                sacc = fmaf(p4[e], c4[e], sacc);
            }
            *(f32x4*)(cr + j * 256 + lane * 4) = p4;
        }
    }
#pragma unroll
    for (int o = 32; o; o >>= 1) sacc += __shfl_xor(sacc, o);
    if (lane == 0) red[w] = sacc;
    __syncthreads();
    if (t == 0) bprt[bid] = red[0] + red[1] + red[2] + red[3];
}

__global__ void k_reduce(const float* __restrict__ bprt, float* __restrict__ out) {
    int t = threadIdx.x;
    float s = bprt[t] + bprt[t + 256];
#pragma unroll
    for (int o = 32; o; o >>= 1) s += __shfl_xor(s, o);
    __shared__ float sm[4];
    if ((t & 63) == 0) sm[t >> 6] = s;
    __syncthreads();
    if (t == 0)
        out[(size_t)BATCH * NQ * NQ] =
            (sm[0] + sm[1] + sm[2] + sm[3]) * (1.0f / BATCH);
}

// ---------------------------------------------------------------- launch
extern "C" void kernel_launch(void* const* d_in, const int* in_sizes, int n_in,
                              void* d_out, int out_size, void* d_ws, size_t ws_size,
                              hipStream_t stream) {
    const float* drone = (const float*)d_in[0];
    const float* sat   = (const float*)d_in[1];
    const float* Wq    = (const float*)d_in[2];
    const float* bq    = (const float*)d_in[3];
    const float* Wk    = (const float*)d_in[4];
    const float* bk    = (const float*)d_in[5];
    float* out = (float*)d_out;

    char* ws = (char*)d_ws;
    ushort* wp0  = (ushort*)ws;                 // 128 KB packed Wq
    ushort* wp1  = (ushort*)(ws + 131072);      // 128 KB packed Wk
    ushort* qkp  = (ushort*)(ws + 262144);      // 16 MB packed q|k (groups 0..1023 q, 1024..2047 k)
    float*  u    = (float*)(ws + 17039360);     // 64 KB
    float*  part = (float*)(ws + 17104896);     // 128 KB col partial sums [16384][2]
    float*  bprt = (float*)(ws + 17235968);     // 2 KB block partials
    float*  cost = out;                         // 64 MiB cost, overwritten by plan in final

    k_prep<<<64, 256, 0, stream>>>(Wq, Wk, wp0, wp1);
    k_proj<<<2048, 256, 0, stream>>>(drone, sat, wp0, wp1, bq, bk, qkp);
    k_cost<<<1024, 256, 0, stream>>>(qkp, cost);
    for (int it = 0; it < 5; it++) {
        k_row<<<512, 256, 0, stream>>>(cost, part, u, it == 0 ? 1 : 0);
        k_col<<<512, 256, 0, stream>>>(cost, u, part);
    }
    k_final<<<512, 256, 0, stream>>>(cost, part, u, bprt);
    k_reduce<<<1, 256, 0, stream>>>(bprt, out);
}

// Round 6
// 151.822 us; speedup vs baseline: 1.6684x; 1.2361x over previous
//
#include <hip/hip_runtime.h>
#include <hip/hip_bf16.h>

// Sizes (fixed by the problem)
#define BATCH 16
#define NQ    1024
#define DM    256
#define NROWS (BATCH * NQ)   // 16384 rows per side
#define RINV  10.0f          // 1/REG

typedef float  f32x4 __attribute__((ext_vector_type(4)));
typedef short  s16x8 __attribute__((ext_vector_type(8)));

static __device__ __forceinline__ ushort f2bf(float f) {
    unsigned u = __builtin_bit_cast(unsigned, f);
    u += 0x7fffu + ((u >> 16) & 1u);
    return (ushort)(u >> 16);
}
static __device__ __forceinline__ float bf2f(ushort h) {
    return __builtin_bit_cast(float, ((unsigned)h) << 16);
}

// Linear-domain Sinkhorn on K~ = exp(-10*cost) stored bf16 (33.5 MB):
//   a = 1/(K~ b),  b = 1/(K~^T a),  plan = a*b*K~,  cost = -0.1*log(K~).
// Identical math to log-domain without max-shift (validated round 5), but the
// 10 streamed passes carry HALF the bytes and ZERO transcendentals.

// ---------------------------------------------------------------- P0: pack W
__global__ void __launch_bounds__(256) k_prep(const float* __restrict__ Wq,
                                              const float* __restrict__ Wk,
                                              ushort* __restrict__ wp0,
                                              ushort* __restrict__ wp1) {
    int gid = blockIdx.x * 256 + threadIdx.x;   // 64 blocks -> gid < 16384
    const float* Wsrc = (gid < 8192) ? Wq : Wk;
    ushort* dst = (gid < 8192) ? wp0 : wp1;
    int gx = gid & 8191;
    int gcol = gx >> 9, kk = (gx >> 6) & 7, ln = gx & 63;
    const float* srow = Wsrc + (size_t)(gcol * 16 + (ln & 15)) * DM
                             + kk * 32 + (ln >> 4) * 8;
    ushort* d = dst + (size_t)gx * 8;
#pragma unroll
    for (int e = 0; e < 8; e++) d[e] = f2bf(srow[e]);
}

// ---------------------------------------------------------------- P1: projection
__global__ void __launch_bounds__(256) k_proj(
        const float* __restrict__ drone, const float* __restrict__ sat,
        const ushort* __restrict__ wp0, const ushort* __restrict__ wp1,
        const float* __restrict__ bq, const float* __restrict__ bk,
        ushort* __restrict__ qkp) {
    __shared__ union {
        float  As[16][260];
        ushort S[16][280];
    } AB;
    __shared__ float red[4][16];

    int t = threadIdx.x;
    int lane = t & 63, w = t >> 6, l16 = lane & 15, lh = lane >> 4;
    int g = blockIdx.x;            // 16-row group 0..2047
    int row0 = g * 16;
    const float* x; const ushort* Wp; const float* bias; int rsrc;
    if (row0 < NROWS) { x = drone; Wp = wp0; bias = bq; rsrc = row0; }
    else              { x = sat;   Wp = wp1; bias = bk; rsrc = row0 - NROWS; }

    {   // stage 16x256 f32 A-tile, coalesced
        int r = t >> 4, c0 = (t & 15) * 4;
        const float* gp = x + (size_t)(rsrc + r) * DM;
#pragma unroll
        for (int j = 0; j < 4; j++)
            *(f32x4*)&AB.As[r][c0 + j * 64] = *(const f32x4*)(gp + c0 + j * 64);
    }
    __syncthreads();

    f32x4 acc[4];
#pragma unroll
    for (int ni = 0; ni < 4; ni++) acc[ni] = f32x4{0.f, 0.f, 0.f, 0.f};
#pragma unroll
    for (int kk = 0; kk < 8; kk++) {
        int k0 = kk * 32 + lh * 8;
        f32x4 a0 = *(const f32x4*)&AB.As[l16][k0];
        f32x4 a1 = *(const f32x4*)&AB.As[l16][k0 + 4];
        s16x8 av;
#pragma unroll
        for (int j = 0; j < 4; j++) {
            av[j]     = (short)f2bf(a0[j]);
            av[j + 4] = (short)f2bf(a1[j]);
        }
#pragma unroll
        for (int ni = 0; ni < 4; ni++) {
            s16x8 bv = *(const s16x8*)(Wp + ((size_t)((w * 4 + ni) * 8 + kk) * 64 + lane) * 8);
            acc[ni] = __builtin_amdgcn_mfma_f32_16x16x32_bf16(av, bv, acc[ni], 0, 0, 0);
        }
    }
    float ssq[4] = {0.f, 0.f, 0.f, 0.f};
#pragma unroll
    for (int ni = 0; ni < 4; ni++) {
        float bcol = bias[w * 64 + ni * 16 + l16];
#pragma unroll
        for (int r = 0; r < 4; r++) {
            acc[ni][r] += bcol;
            ssq[r] += acc[ni][r] * acc[ni][r];
        }
    }
#pragma unroll
    for (int off = 1; off < 16; off <<= 1)
#pragma unroll
        for (int r = 0; r < 4; r++) ssq[r] += __shfl_xor(ssq[r], off);
    if (l16 == 0)
#pragma unroll
        for (int r = 0; r < 4; r++) red[w][lh * 4 + r] = ssq[r];
    __syncthreads();

    float inv[4];
#pragma unroll
    for (int r = 0; r < 4; r++) {
        int row = lh * 4 + r;
        float tot = red[0][row] + red[1][row] + red[2][row] + red[3][row];
        inv[r] = 1.0f / fmaxf(sqrtf(tot), 1e-12f);
    }
#pragma unroll
    for (int ni = 0; ni < 4; ni++)
#pragma unroll
        for (int r = 0; r < 4; r++)
            AB.S[lh * 4 + r][w * 64 + ni * 16 + l16] = f2bf(acc[ni][r] * inv[r]);
    __syncthreads();
#pragma unroll
    for (int h = 0; h < 2; h++) {
        int kk = w + h * 4;
        s16x8 vv = *(const s16x8*)&AB.S[l16][kk * 32 + lh * 8];
        *(s16x8*)(qkp + ((size_t)(g * 8 + kk) * 64 + lane) * 8) = vv;
    }
}

// ---------------------------------------------------------------- P2: K~ GEMM
// 1024 blocks; 128x128 tile; epilogue K~ = exp(10*dot - 10) stored bf16.
__global__ void __launch_bounds__(256) k_cost(const ushort* __restrict__ qkp,
                                              char* __restrict__ ktc, int kstride) {
    int t = threadIdx.x, lane = t & 63, w = t >> 6;
    int l16 = lane & 15, lh = lane >> 4;
    int tile = blockIdx.x;
    int b = tile >> 6, ty = (tile >> 3) & 7, tx = tile & 7;
    int rg  = b * 64 + ty * 8 + (w >> 1) * 4;
    int cgp = 1024 + b * 64 + tx * 8 + (w & 1) * 4;
    f32x4 acc[4][4];
#pragma unroll
    for (int i = 0; i < 4; i++)
#pragma unroll
        for (int j = 0; j < 4; j++) acc[i][j] = f32x4{0.f, 0.f, 0.f, 0.f};
#pragma unroll
    for (int kk = 0; kk < 8; kk++) {
        s16x8 am[4], bn[4];
#pragma unroll
        for (int mi = 0; mi < 4; mi++)
            am[mi] = *(const s16x8*)(qkp + ((size_t)((rg + mi) * 8 + kk) * 64 + lane) * 8);
#pragma unroll
        for (int ni = 0; ni < 4; ni++)
            bn[ni] = *(const s16x8*)(qkp + ((size_t)((cgp + ni) * 8 + kk) * 64 + lane) * 8);
#pragma unroll
        for (int mi = 0; mi < 4; mi++)
#pragma unroll
            for (int ni = 0; ni < 4; ni++)
                acc[mi][ni] = __builtin_amdgcn_mfma_f32_16x16x32_bf16(
                    am[mi], bn[ni], acc[mi][ni], 0, 0, 0);
    }
    int rl = ty * 128 + (w >> 1) * 64, cl = tx * 128 + (w & 1) * 64;
#pragma unroll
    for (int mi = 0; mi < 4; mi++)
#pragma unroll
        for (int r = 0; r < 4; r++) {
            int row = rl + mi * 16 + lh * 4 + r;
            ushort* orow = (ushort*)(ktc + (size_t)(b * NQ + row) * (size_t)kstride);
#pragma unroll
            for (int ni = 0; ni < 4; ni++)
                orow[cl + ni * 16 + l16] =
                    f2bf(__expf(fmaf(RINV, acc[mi][ni][r], -RINV)));
        }
}

// ---------------------------------------------------------------- row matvec:
// a[row] = 1 / sum_m K~[row,m] * b[m].  1024 blocks x 16 rows.
template<int FIRST>
__global__ void __launch_bounds__(256) k_row(const char* __restrict__ ktc, int kstride,
                                             const float* __restrict__ part,
                                             float* __restrict__ u) {
    __shared__ float vsh[NQ];
    int bid = blockIdx.x, t = threadIdx.x;
    int lane = t & 63, w = t >> 6;
    int b = bid >> 6;                  // 64 blocks per batch
    if (FIRST) {
#pragma unroll
        for (int j = 0; j < 4; j++) vsh[t * 4 + j] = 1.0f;
    } else {
        const f32x4* pp = (const f32x4*)&part[((size_t)(b << 10) + t * 4) * 8];
#pragma unroll
        for (int j = 0; j < 4; j++) {
            f32x4 A = pp[j * 2], B = pp[j * 2 + 1];
            vsh[t * 4 + j] =
                1.0f / (((A[0] + A[1]) + (A[2] + A[3])) + ((B[0] + B[1]) + (B[2] + B[3])));
        }
    }
    __syncthreads();
    float br0[8], br1[8];
#pragma unroll
    for (int j = 0; j < 8; j++) {
        br0[j] = vsh[lane * 8 + j];
        br1[j] = vsh[512 + lane * 8 + j];
    }
#pragma unroll
    for (int rr = 0; rr < 4; rr++) {
        int row = bid * 16 + w * 4 + rr;
        const ushort* kr = (const ushort*)(ktc + (size_t)row * (size_t)kstride);
        s16x8 k0 = *(const s16x8*)(kr + lane * 8);
        s16x8 k1 = *(const s16x8*)(kr + 512 + lane * 8);
        float s = 0.f;
#pragma unroll
        for (int j = 0; j < 8; j++) {
            s = fmaf(bf2f((ushort)k0[j]), br0[j], s);
            s = fmaf(bf2f((ushort)k1[j]), br1[j], s);
        }
#pragma unroll
        for (int o = 32; o; o >>= 1) s += __shfl_xor(s, o);
        if (lane == 0) u[row] = 1.0f / s;
    }
}

// ---------------------------------------------------------------- col matvec:
// part[b,m,ch] = sum over 128-row chunk of K~[n,m]*a[n].  1024 blocks.
__global__ void __launch_bounds__(256) k_col(const char* __restrict__ ktc, int kstride,
                                             const float* __restrict__ u,
                                             float* __restrict__ part) {
    __shared__ float ash[128];
    __shared__ float2 sred[4][64];
    int bid = blockIdx.x, t = threadIdx.x;
    int lane = t & 63, w = t >> 6;
    int b = bid >> 6, cg = (bid >> 3) & 7, ch = bid & 7;
    int c0 = cg * 128, n0 = ch * 128;
    if (t < 128) ash[t] = u[(b << 10) + n0 + t];
    __syncthreads();
    int m0 = c0 + lane * 2;
    const char* base = ktc + (size_t)((b << 10) + n0 + w * 32) * (size_t)kstride + m0 * 2;
    float s0 = 0.f, s1 = 0.f;
#pragma unroll 8
    for (int i = 0; i < 32; i++) {
        ushort2 kk = *(const ushort2*)(base + (size_t)i * (size_t)kstride);
        float a = ash[w * 32 + i];
        s0 = fmaf(bf2f(kk.x), a, s0);
        s1 = fmaf(bf2f(kk.y), a, s1);
    }
    sred[w][lane] = float2{s0, s1};
    __syncthreads();
    if (w == 0) {
        float2 A = sred[0][lane], B = sred[1][lane], C = sred[2][lane], D = sred[3][lane];
        size_t pb = ((size_t)(b << 10) + m0) * 8 + ch;
        part[pb]     = (A.x + B.x) + (C.x + D.x);
        part[pb + 8] = (A.y + B.y) + (C.y + D.y);
    }
}

// ---------------------------------------------------------------- final:
// plan = a*b*K~ (f32 to d_out), ot partial = sum plan * (-0.1*log K~).
__global__ void __launch_bounds__(256) k_final(const char* __restrict__ ktc, int kstride,
                                               const float* __restrict__ part,
                                               const float* __restrict__ u,
                                               float* __restrict__ out,
                                               float* __restrict__ bprt) {
    __shared__ float vsh[NQ];
    __shared__ float red[4];
    int bid = blockIdx.x, t = threadIdx.x;
    int lane = t & 63, w = t >> 6;
    int b = bid >> 6;
    {
        const f32x4* pp = (const f32x4*)&part[((size_t)(b << 10) + t * 4) * 8];
#pragma unroll
        for (int j = 0; j < 4; j++) {
            f32x4 A = pp[j * 2], B = pp[j * 2 + 1];
            vsh[t * 4 + j] =
                1.0f / (((A[0] + A[1]) + (A[2] + A[3])) + ((B[0] + B[1]) + (B[2] + B[3])));
        }
    }
    __syncthreads();
    float br0[8], br1[8];
#pragma unroll
    for (int j = 0; j < 8; j++) {
        br0[j] = vsh[lane * 8 + j];
        br1[j] = vsh[512 + lane * 8 + j];
    }
    float sacc = 0.f;
#pragma unroll
    for (int rr = 0; rr < 4; rr++) {
        int row = bid * 16 + w * 4 + rr;
        const ushort* kr = (const ushort*)(ktc + (size_t)row * (size_t)kstride);
        s16x8 k0 = *(const s16x8*)(kr + lane * 8);
        s16x8 k1 = *(const s16x8*)(kr + 512 + lane * 8);
        float a = u[row];
        float* orow = out + (size_t)row * NQ;
        float pv0[8], pv1[8];
#pragma unroll
        for (int j = 0; j < 8; j++) {
            float kf0 = bf2f((ushort)k0[j]);
            float kf1 = bf2f((ushort)k1[j]);
            float p0 = a * br0[j] * kf0;
            float p1 = a * br1[j] * kf1;
            sacc = fmaf(p0, -0.1f * __logf(kf0), sacc);
            sacc = fmaf(p1, -0.1f * __logf(kf1), sacc);
            pv0[j] = p0; pv1[j] = p1;
        }
        *(f32x4*)(orow + lane * 8)           = *(f32x4*)&pv0[0];
        *(f32x4*)(orow + lane * 8 + 4)       = *(f32x4*)&pv0[4];
        *(f32x4*)(orow + 512 + lane * 8)     = *(f32x4*)&pv1[0];
        *(f32x4*)(orow + 512 + lane * 8 + 4) = *(f32x4*)&pv1[4];
    }
#pragma unroll
    for (int o = 32; o; o >>= 1) sacc += __shfl_xor(sacc, o);
    if (lane == 0) red[w] = sacc;
    __syncthreads();
    if (t == 0) bprt[bid] = red[0] + red[1] + red[2] + red[3];
}

__global__ void k_reduce(const float* __restrict__ bprt, float* __restrict__ out) {
    int t = threadIdx.x;
    float s = (bprt[t] + bprt[t + 256]) + (bprt[t + 512] + bprt[t + 768]);
#pragma unroll
    for (int o = 32; o; o >>= 1) s += __shfl_xor(s, o);
    __shared__ float sm[4];
    if ((t & 63) == 0) sm[t >> 6] = s;
    __syncthreads();
    if (t == 0)
        out[(size_t)BATCH * NQ * NQ] =
            (sm[0] + sm[1] + sm[2] + sm[3]) * (1.0f / BATCH);
}

// ---------------------------------------------------------------- launch
extern "C" void kernel_launch(void* const* d_in, const int* in_sizes, int n_in,
                              void* d_out, int out_size, void* d_ws, size_t ws_size,
                              hipStream_t stream) {
    const float* drone = (const float*)d_in[0];
    const float* sat   = (const float*)d_in[1];
    const float* Wq    = (const float*)d_in[2];
    const float* bq    = (const float*)d_in[3];
    const float* Wk    = (const float*)d_in[4];
    const float* bk    = (const float*)d_in[5];
    float* out = (float*)d_out;

    char* ws = (char*)d_ws;
    ushort* wp0  = (ushort*)ws;                 // 128 KB packed Wq
    ushort* wp1  = (ushort*)(ws + 131072);      // 128 KB packed Wk
    ushort* qkp  = (ushort*)(ws + 262144);      // 16 MB packed q|k
    float*  u    = (float*)(ws + 17039360);     // 64 KB: a potentials
    float*  part = (float*)(ws + 17104896);     // 512 KB col partials [16][1024][8]
    float*  bprt = (float*)(ws + 17629184);     // 4 KB block partials

    // K~ bf16: in ws if it fits (evidence: ws = 256 MiB), else interleaved into
    // d_out rows (bytes row*4096..+2048; final reads-then-overwrites its own rows).
    char* ktc; int kstride;
    if (ws_size >= (size_t)51187712) { ktc = ws + 17633280; kstride = 2048; }
    else                             { ktc = (char*)d_out;  kstride = 4096; }

    k_prep<<<64, 256, 0, stream>>>(Wq, Wk, wp0, wp1);
    k_proj<<<2048, 256, 0, stream>>>(drone, sat, wp0, wp1, bq, bk, qkp);
    k_cost<<<1024, 256, 0, stream>>>(qkp, ktc, kstride);
    for (int it = 0; it < 5; it++) {
        if (it == 0) k_row<1><<<1024, 256, 0, stream>>>(ktc, kstride, part, u);
        else         k_row<0><<<1024, 256, 0, stream>>>(ktc, kstride, part, u);
        k_col<<<1024, 256, 0, stream>>>(ktc, kstride, u, part);
    }
    k_final<<<1024, 256, 0, stream>>>(ktc, kstride, part, u, out, bprt);
    k_reduce<<<1, 256, 0, stream>>>(bprt, out);
}

// Round 7
// 121.099 us; speedup vs baseline: 2.0917x; 1.2537x over previous
//
#include <hip/hip_runtime.h>
#include <hip/hip_bf16.h>

// Sizes (fixed by the problem)
#define BATCH 16
#define NQ    1024
#define DM    256
#define NROWS (BATCH * NQ)   // 16384 rows per side
#define RINV  10.0f          // 1/REG

typedef float  f32x4 __attribute__((ext_vector_type(4)));
typedef short  s16x8 __attribute__((ext_vector_type(8)));

static __device__ __forceinline__ ushort f2bf(float f) {
    unsigned u = __builtin_bit_cast(unsigned, f);
    u += 0x7fffu + ((u >> 16) & 1u);
    return (ushort)(u >> 16);
}
static __device__ __forceinline__ float bf2f(ushort h) {
    return __builtin_bit_cast(float, ((unsigned)h) << 16);
}

// Linear-domain Sinkhorn on K~ = exp(-10*cost) stored bf16 (33.5 MB):
//   a = 1/(K~ b),  b = 1/(K~^T a),  plan = a*b*K~,  cost = -0.1*log(K~).
// NEW this round: one fused kernel per iteration does BOTH the a-update and
// the b-column-partials in a single pass over K~ (row-major streaming), with
// per-block partial column sums ping-ponged between two buffers.

// ---------------------------------------------------------------- P0: pack W
__global__ void __launch_bounds__(256) k_prep(const float* __restrict__ Wq,
                                              const float* __restrict__ Wk,
                                              ushort* __restrict__ wp0,
                                              ushort* __restrict__ wp1) {
    int gid = blockIdx.x * 256 + threadIdx.x;   // 64 blocks -> gid < 16384
    const float* Wsrc = (gid < 8192) ? Wq : Wk;
    ushort* dst = (gid < 8192) ? wp0 : wp1;
    int gx = gid & 8191;
    int gcol = gx >> 9, kk = (gx >> 6) & 7, ln = gx & 63;
    const float* srow = Wsrc + (size_t)(gcol * 16 + (ln & 15)) * DM
                             + kk * 32 + (ln >> 4) * 8;
    ushort* d = dst + (size_t)gx * 8;
#pragma unroll
    for (int e = 0; e < 8; e++) d[e] = f2bf(srow[e]);
}

// ---------------------------------------------------------------- P1: projection
__global__ void __launch_bounds__(256) k_proj(
        const float* __restrict__ drone, const float* __restrict__ sat,
        const ushort* __restrict__ wp0, const ushort* __restrict__ wp1,
        const float* __restrict__ bq, const float* __restrict__ bk,
        ushort* __restrict__ qkp) {
    __shared__ union {
        float  As[16][260];
        ushort S[16][280];
    } AB;
    __shared__ float red[4][16];

    int t = threadIdx.x;
    int lane = t & 63, w = t >> 6, l16 = lane & 15, lh = lane >> 4;
    int g = blockIdx.x;            // 16-row group 0..2047
    int row0 = g * 16;
    const float* x; const ushort* Wp; const float* bias; int rsrc;
    if (row0 < NROWS) { x = drone; Wp = wp0; bias = bq; rsrc = row0; }
    else              { x = sat;   Wp = wp1; bias = bk; rsrc = row0 - NROWS; }

    {   // stage 16x256 f32 A-tile, coalesced
        int r = t >> 4, c0 = (t & 15) * 4;
        const float* gp = x + (size_t)(rsrc + r) * DM;
#pragma unroll
        for (int j = 0; j < 4; j++)
            *(f32x4*)&AB.As[r][c0 + j * 64] = *(const f32x4*)(gp + c0 + j * 64);
    }
    __syncthreads();

    f32x4 acc[4];
#pragma unroll
    for (int ni = 0; ni < 4; ni++) acc[ni] = f32x4{0.f, 0.f, 0.f, 0.f};
#pragma unroll
    for (int kk = 0; kk < 8; kk++) {
        int k0 = kk * 32 + lh * 8;
        f32x4 a0 = *(const f32x4*)&AB.As[l16][k0];
        f32x4 a1 = *(const f32x4*)&AB.As[l16][k0 + 4];
        s16x8 av;
#pragma unroll
        for (int j = 0; j < 4; j++) {
            av[j]     = (short)f2bf(a0[j]);
            av[j + 4] = (short)f2bf(a1[j]);
        }
#pragma unroll
        for (int ni = 0; ni < 4; ni++) {
            s16x8 bv = *(const s16x8*)(Wp + ((size_t)((w * 4 + ni) * 8 + kk) * 64 + lane) * 8);
            acc[ni] = __builtin_amdgcn_mfma_f32_16x16x32_bf16(av, bv, acc[ni], 0, 0, 0);
        }
    }
    float ssq[4] = {0.f, 0.f, 0.f, 0.f};
#pragma unroll
    for (int ni = 0; ni < 4; ni++) {
        float bcol = bias[w * 64 + ni * 16 + l16];
#pragma unroll
        for (int r = 0; r < 4; r++) {
            acc[ni][r] += bcol;
            ssq[r] += acc[ni][r] * acc[ni][r];
        }
    }
#pragma unroll
    for (int off = 1; off < 16; off <<= 1)
#pragma unroll
        for (int r = 0; r < 4; r++) ssq[r] += __shfl_xor(ssq[r], off);
    if (l16 == 0)
#pragma unroll
        for (int r = 0; r < 4; r++) red[w][lh * 4 + r] = ssq[r];
    __syncthreads();

    float inv[4];
#pragma unroll
    for (int r = 0; r < 4; r++) {
        int row = lh * 4 + r;
        float tot = red[0][row] + red[1][row] + red[2][row] + red[3][row];
        inv[r] = 1.0f / fmaxf(sqrtf(tot), 1e-12f);
    }
#pragma unroll
    for (int ni = 0; ni < 4; ni++)
#pragma unroll
        for (int r = 0; r < 4; r++)
            AB.S[lh * 4 + r][w * 64 + ni * 16 + l16] = f2bf(acc[ni][r] * inv[r]);
    __syncthreads();
#pragma unroll
    for (int h = 0; h < 2; h++) {
        int kk = w + h * 4;
        s16x8 vv = *(const s16x8*)&AB.S[l16][kk * 32 + lh * 8];
        *(s16x8*)(qkp + ((size_t)(g * 8 + kk) * 64 + lane) * 8) = vv;
    }
}

// ---------------------------------------------------------------- P2: K~ GEMM
__global__ void __launch_bounds__(256) k_cost(const ushort* __restrict__ qkp,
                                              char* __restrict__ ktc, int kstride) {
    int t = threadIdx.x, lane = t & 63, w = t >> 6;
    int l16 = lane & 15, lh = lane >> 4;
    int tile = blockIdx.x;
    int b = tile >> 6, ty = (tile >> 3) & 7, tx = tile & 7;
    int rg  = b * 64 + ty * 8 + (w >> 1) * 4;
    int cgp = 1024 + b * 64 + tx * 8 + (w & 1) * 4;
    f32x4 acc[4][4];
#pragma unroll
    for (int i = 0; i < 4; i++)
#pragma unroll
        for (int j = 0; j < 4; j++) acc[i][j] = f32x4{0.f, 0.f, 0.f, 0.f};
#pragma unroll
    for (int kk = 0; kk < 8; kk++) {
        s16x8 am[4], bn[4];
#pragma unroll
        for (int mi = 0; mi < 4; mi++)
            am[mi] = *(const s16x8*)(qkp + ((size_t)((rg + mi) * 8 + kk) * 64 + lane) * 8);
#pragma unroll
        for (int ni = 0; ni < 4; ni++)
            bn[ni] = *(const s16x8*)(qkp + ((size_t)((cgp + ni) * 8 + kk) * 64 + lane) * 8);
#pragma unroll
        for (int mi = 0; mi < 4; mi++)
#pragma unroll
            for (int ni = 0; ni < 4; ni++)
                acc[mi][ni] = __builtin_amdgcn_mfma_f32_16x16x32_bf16(
                    am[mi], bn[ni], acc[mi][ni], 0, 0, 0);
    }
    int rl = ty * 128 + (w >> 1) * 64, cl = tx * 128 + (w & 1) * 64;
#pragma unroll
    for (int mi = 0; mi < 4; mi++)
#pragma unroll
        for (int r = 0; r < 4; r++) {
            int row = rl + mi * 16 + lh * 4 + r;
            ushort* orow = (ushort*)(ktc + (size_t)(b * NQ + row) * (size_t)kstride);
#pragma unroll
            for (int ni = 0; ni < 4; ni++)
                orow[cl + ni * 16 + l16] =
                    f2bf(__expf(fmaf(RINV, acc[mi][ni][r], -RINV)));
        }
}

// ---------------------------------------------------------------- fused Sinkhorn iter:
// block = (batch b, 32-row chunk ch).  Recombine b[m]=1/sum(partin), then one
// pass over this chunk's K~ rows: a[n]=1/(row.b); col-partials += K~[n,m]*a[n].
// partout[(b*32+ch)*1024 + m].  512 blocks.
template<int FIRST>
__global__ void __launch_bounds__(256) k_sink(const char* __restrict__ ktc, int kstride,
                                              const float* __restrict__ partin,
                                              float* __restrict__ u,
                                              float* __restrict__ partout) {
    __shared__ float bsh[NQ];
    __shared__ float pcol[4][NQ];
    int bid = blockIdx.x, t = threadIdx.x;
    int lane = t & 63, w = t >> 6;
    int b = bid >> 5, ch = bid & 31;

    if (FIRST) {
        *(f32x4*)&bsh[t * 4] = f32x4{1.f, 1.f, 1.f, 1.f};
    } else {
        f32x4 s = f32x4{0.f, 0.f, 0.f, 0.f};
        const float* pb = partin + (size_t)b * 32 * NQ + t * 4;
#pragma unroll 8
        for (int c = 0; c < 32; c++)
            s += *(const f32x4*)(pb + c * NQ);
        f32x4 r;
#pragma unroll
        for (int j = 0; j < 4; j++) r[j] = 1.0f / s[j];
        *(f32x4*)&bsh[t * 4] = r;
    }
#pragma unroll
    for (int r = 0; r < 4; r++) *(f32x4*)&pcol[r][t * 4] = f32x4{0.f, 0.f, 0.f, 0.f};
    __syncthreads();

    float br0[8], br1[8];
#pragma unroll
    for (int j = 0; j < 8; j++) {
        br0[j] = bsh[lane * 8 + j];
        br1[j] = bsh[512 + lane * 8 + j];
    }

    float pa0[8], pa1[8];
#pragma unroll
    for (int j = 0; j < 8; j++) { pa0[j] = 0.f; pa1[j] = 0.f; }

    int rowbase = (b << 10) + ch * 32 + w * 8;   // global row of this wave's first row
#pragma unroll
    for (int rp = 0; rp < 4; rp++) {             // 2 rows per strip for ILP
        const ushort* ra = (const ushort*)(ktc + (size_t)(rowbase + rp * 2) * (size_t)kstride);
        const ushort* rb = (const ushort*)(ktc + (size_t)(rowbase + rp * 2 + 1) * (size_t)kstride);
        s16x8 ka0 = *(const s16x8*)(ra + lane * 8);
        s16x8 ka1 = *(const s16x8*)(ra + 512 + lane * 8);
        s16x8 kb0 = *(const s16x8*)(rb + lane * 8);
        s16x8 kb1 = *(const s16x8*)(rb + 512 + lane * 8);
        float sa = 0.f, sb = 0.f;
#pragma unroll
        for (int j = 0; j < 8; j++) {
            sa = fmaf(bf2f((ushort)ka0[j]), br0[j], sa);
            sa = fmaf(bf2f((ushort)ka1[j]), br1[j], sa);
            sb = fmaf(bf2f((ushort)kb0[j]), br0[j], sb);
            sb = fmaf(bf2f((ushort)kb1[j]), br1[j], sb);
        }
#pragma unroll
        for (int o = 32; o; o >>= 1) {
            sa += __shfl_xor(sa, o);
            sb += __shfl_xor(sb, o);
        }
        float aa = 1.0f / sa, ab = 1.0f / sb;
        if (lane == 0) {
            u[rowbase + rp * 2]     = aa;
            u[rowbase + rp * 2 + 1] = ab;
        }
#pragma unroll
        for (int j = 0; j < 8; j++) {
            pa0[j] = fmaf(bf2f((ushort)ka0[j]), aa, pa0[j]);
            pa0[j] = fmaf(bf2f((ushort)kb0[j]), ab, pa0[j]);
            pa1[j] = fmaf(bf2f((ushort)ka1[j]), aa, pa1[j]);
            pa1[j] = fmaf(bf2f((ushort)kb1[j]), ab, pa1[j]);
        }
    }
#pragma unroll
    for (int j = 0; j < 8; j++) {
        pcol[w][lane * 8 + j]       = pa0[j];
        pcol[w][512 + lane * 8 + j] = pa1[j];
    }
    __syncthreads();
    {
        f32x4 s = *(const f32x4*)&pcol[0][t * 4];
        s += *(const f32x4*)&pcol[1][t * 4];
        s += *(const f32x4*)&pcol[2][t * 4];
        s += *(const f32x4*)&pcol[3][t * 4];
        *(f32x4*)&partout[((size_t)b * 32 + ch) * NQ + t * 4] = s;
    }
}

// ---------------------------------------------------------------- final:
// recombine b; plan = a*b*K~ (f32 to d_out); ot partial = sum plan*(-0.1*logK~).
__global__ void __launch_bounds__(256) k_final(const char* __restrict__ ktc, int kstride,
                                               const float* __restrict__ partin,
                                               const float* __restrict__ u,
                                               float* __restrict__ out,
                                               float* __restrict__ bprt) {
    __shared__ float bsh[NQ];
    __shared__ float red[4];
    int bid = blockIdx.x, t = threadIdx.x;
    int lane = t & 63, w = t >> 6;
    int b = bid >> 5, ch = bid & 31;
    {
        f32x4 s = f32x4{0.f, 0.f, 0.f, 0.f};
        const float* pb = partin + (size_t)b * 32 * NQ + t * 4;
#pragma unroll 8
        for (int c = 0; c < 32; c++)
            s += *(const f32x4*)(pb + c * NQ);
        f32x4 r;
#pragma unroll
        for (int j = 0; j < 4; j++) r[j] = 1.0f / s[j];
        *(f32x4*)&bsh[t * 4] = r;
    }
    __syncthreads();

    float br0[8], br1[8];
#pragma unroll
    for (int j = 0; j < 8; j++) {
        br0[j] = bsh[lane * 8 + j];
        br1[j] = bsh[512 + lane * 8 + j];
    }
    float sacc = 0.f;
    int rowbase = (b << 10) + ch * 32 + w * 8;
#pragma unroll
    for (int rr = 0; rr < 8; rr++) {
        int row = rowbase + rr;
        const ushort* kr = (const ushort*)(ktc + (size_t)row * (size_t)kstride);
        s16x8 k0 = *(const s16x8*)(kr + lane * 8);
        s16x8 k1 = *(const s16x8*)(kr + 512 + lane * 8);
        float a = u[row];
        float* orow = out + (size_t)row * NQ;
        float pv0[8], pv1[8];
#pragma unroll
        for (int j = 0; j < 8; j++) {
            float kf0 = bf2f((ushort)k0[j]);
            float kf1 = bf2f((ushort)k1[j]);
            float p0 = a * br0[j] * kf0;
            float p1 = a * br1[j] * kf1;
            sacc = fmaf(p0, -0.1f * __logf(kf0), sacc);
            sacc = fmaf(p1, -0.1f * __logf(kf1), sacc);
            pv0[j] = p0; pv1[j] = p1;
        }
        *(f32x4*)(orow + lane * 8)           = *(f32x4*)&pv0[0];
        *(f32x4*)(orow + lane * 8 + 4)       = *(f32x4*)&pv0[4];
        *(f32x4*)(orow + 512 + lane * 8)     = *(f32x4*)&pv1[0];
        *(f32x4*)(orow + 512 + lane * 8 + 4) = *(f32x4*)&pv1[4];
    }
#pragma unroll
    for (int o = 32; o; o >>= 1) sacc += __shfl_xor(sacc, o);
    if (lane == 0) red[w] = sacc;
    __syncthreads();
    if (t == 0) bprt[bid] = red[0] + red[1] + red[2] + red[3];
}

__global__ void k_reduce(const float* __restrict__ bprt, float* __restrict__ out) {
    int t = threadIdx.x;
    float s = bprt[t] + bprt[t + 256];
#pragma unroll
    for (int o = 32; o; o >>= 1) s += __shfl_xor(s, o);
    __shared__ float sm[4];
    if ((t & 63) == 0) sm[t >> 6] = s;
    __syncthreads();
    if (t == 0)
        out[(size_t)BATCH * NQ * NQ] =
            (sm[0] + sm[1] + sm[2] + sm[3]) * (1.0f / BATCH);
}

// ---------------------------------------------------------------- launch
extern "C" void kernel_launch(void* const* d_in, const int* in_sizes, int n_in,
                              void* d_out, int out_size, void* d_ws, size_t ws_size,
                              hipStream_t stream) {
    const float* drone = (const float*)d_in[0];
    const float* sat   = (const float*)d_in[1];
    const float* Wq    = (const float*)d_in[2];
    const float* bq    = (const float*)d_in[3];
    const float* Wk    = (const float*)d_in[4];
    const float* bk    = (const float*)d_in[5];
    float* out = (float*)d_out;

    char* ws = (char*)d_ws;
    ushort* wp0   = (ushort*)ws;                 // 128 KB packed Wq
    ushort* wp1   = (ushort*)(ws + 131072);      // 128 KB packed Wk
    ushort* qkp   = (ushort*)(ws + 262144);      // 16 MB packed q|k
    float*  u     = (float*)(ws + 17039360);     // 64 KB: a potentials
    float*  partA = (float*)(ws + 17104896);     // 2 MB col partials [16][32][1024]
    float*  partB = (float*)(ws + 19202048);     // 2 MB ping-pong
    float*  bprt  = (float*)(ws + 21299200);     // 2 KB block partials

    // K~ bf16 (32 MB): in ws if it fits (evidence: ws = 256 MiB), else
    // interleaved into d_out rows (row i bytes i*4096..+2048; per-lane
    // read-before-write makes k_final safe).
    char* ktc; int kstride;
    if (ws_size >= (size_t)54000000) { ktc = ws + 21303296; kstride = 2048; }
    else                             { ktc = (char*)d_out;  kstride = 4096; }

    k_prep<<<64, 256, 0, stream>>>(Wq, Wk, wp0, wp1);
    k_proj<<<2048, 256, 0, stream>>>(drone, sat, wp0, wp1, bq, bk, qkp);
    k_cost<<<1024, 256, 0, stream>>>(qkp, ktc, kstride);

    k_sink<1><<<512, 256, 0, stream>>>(ktc, kstride, nullptr, u, partA);  // it 1
    k_sink<0><<<512, 256, 0, stream>>>(ktc, kstride, partA, u, partB);    // it 2
    k_sink<0><<<512, 256, 0, stream>>>(ktc, kstride, partB, u, partA);    // it 3
    k_sink<0><<<512, 256, 0, stream>>>(ktc, kstride, partA, u, partB);    // it 4
    k_sink<0><<<512, 256, 0, stream>>>(ktc, kstride, partB, u, partA);    // it 5

    k_final<<<512, 256, 0, stream>>>(ktc, kstride, partA, u, out, bprt);
    k_reduce<<<1, 256, 0, stream>>>(bprt, out);
}